// Round 1
// baseline (392.869 us; speedup 1.0000x reference)
//
#include <hip/hip_runtime.h>

#define B_DIM 16
#define C_DIM 256
#define L_DIM 8192
#define D_INNER 512
#define ATT 64

// ws layout (floats):
//   [0]                     qk_scale = <wq,wk>/sqrt(64)
//   [64 .. 64+512)          wo_v[d] = sum_a w_out[d][a]*wv[a]
//   [1024 .. 1024+B*L)      pooled[b][l]

__global__ __launch_bounds__(512) void prep_kernel(
    const float* __restrict__ wq, const float* __restrict__ wk,
    const float* __restrict__ wv, const float* __restrict__ w_out,
    float* __restrict__ ws) {
    int d = threadIdx.x;  // 0..511
    float acc = 0.f;
    #pragma unroll
    for (int a = 0; a < ATT; ++a) acc += w_out[d * ATT + a] * wv[a];
    ws[64 + d] = acc;
    if (d == 0) {
        float qk = 0.f;
        #pragma unroll
        for (int a = 0; a < ATT; ++a) qk += wq[a] * wk[a];
        ws[0] = qk * 0.125f;  // 1/sqrt(ATT) = 1/8
    }
}

// One thread per 2 consecutive l (float2). tid = b*(L/2) + l2.
__global__ __launch_bounds__(256) void pooled_kernel(
    const float* __restrict__ h_v, const float* __restrict__ ws,
    float* __restrict__ pooled) {
    const float t_scale = ws[0];
    int tid = blockIdx.x * blockDim.x + threadIdx.x;  // 0..65535
    int b  = tid >> 12;          // L/2 = 4096 float2 per b
    int l2 = tid & 4095;
    const float2* src = (const float2*)(h_v + (size_t)b * C_DIM * L_DIM) + l2;

    // Pass 1: sum / min / max over c
    float s0 = 0.f, s1 = 0.f;
    float mn0 = __builtin_inff(), mn1 = __builtin_inff();
    float mx0 = -__builtin_inff(), mx1 = -__builtin_inff();
    #pragma unroll 8
    for (int c = 0; c < C_DIM; ++c) {
        float2 v = src[(size_t)c * (L_DIM / 2)];
        s0 += v.x; s1 += v.y;
        mn0 = fminf(mn0, v.x); mx0 = fmaxf(mx0, v.x);
        mn1 = fminf(mn1, v.y); mx1 = fmaxf(mx1, v.y);
    }
    float t0 = s0 * (1.0f / C_DIM) * t_scale;
    float t1 = s1 * (1.0f / C_DIM) * t_scale;
    // logits = h*t ; max over c is t*min or t*max depending on sign of t
    float m0 = fmaxf(mn0 * t0, mx0 * t0);
    float m1 = fmaxf(mn1 * t1, mx1 * t1);

    // Pass 2: softmax-weighted pooling (mostly L3-resident re-read)
    float se0 = 0.f, se1 = 0.f, sp0 = 0.f, sp1 = 0.f;
    #pragma unroll 8
    for (int c = 0; c < C_DIM; ++c) {
        float2 v = src[(size_t)c * (L_DIM / 2)];
        float e0 = __expf(v.x * t0 - m0);
        float e1 = __expf(v.y * t1 - m1);
        se0 += e0; se1 += e1;
        sp0 += e0 * v.x; sp1 += e1 * v.y;
    }
    float2 o;
    o.x = sp0 / se0;
    o.y = sp1 / se1;
    ((float2*)pooled)[tid] = o;  // = pooled[b*L + l], coalesced
}

// out[b,d,l] = pooled[b,l] * wo_v[d]; one float4 per thread, pure stream write.
__global__ __launch_bounds__(256) void write_kernel(
    const float* __restrict__ ws, float* __restrict__ out) {
    const float* wo_v   = ws + 64;
    const float* pooled = ws + 1024;
    int i   = blockIdx.x * 256 + threadIdx.x;  // float4 index, 0..16777215
    int l4  = i & 2047;                        // L/4 = 2048
    int tmp = i >> 11;
    int d   = tmp & 511;
    int b   = tmp >> 9;
    float4 p = ((const float4*)(pooled + (size_t)b * L_DIM))[l4];
    float  w = wo_v[d];
    float4 o;
    o.x = p.x * w; o.y = p.y * w; o.z = p.z * w; o.w = p.w * w;
    ((float4*)out)[i] = o;
}

extern "C" void kernel_launch(void* const* d_in, const int* in_sizes, int n_in,
                              void* d_out, int out_size, void* d_ws, size_t ws_size,
                              hipStream_t stream) {
    const float* h_v   = (const float*)d_in[0];
    const float* wq    = (const float*)d_in[1];
    const float* wk    = (const float*)d_in[2];
    const float* wv    = (const float*)d_in[3];
    const float* w_out = (const float*)d_in[4];
    float* ws  = (float*)d_ws;
    float* out = (float*)d_out;

    hipLaunchKernelGGL(prep_kernel, dim3(1), dim3(512), 0, stream,
                       wq, wk, wv, w_out, ws);
    // B*L/2 = 65536 threads
    hipLaunchKernelGGL(pooled_kernel, dim3(256), dim3(256), 0, stream,
                       h_v, ws, ws + 1024);
    // B*D*L/4 = 16777216 float4 stores
    hipLaunchKernelGGL(write_kernel, dim3(65536), dim3(256), 0, stream,
                       ws, out);
}